// Round 9
// baseline (172.087 us; speedup 1.0000x reference)
//
#include <hip/hip_runtime.h>

typedef __attribute__((ext_vector_type(8))) short short8;
typedef _Float16 half8 __attribute__((ext_vector_type(8)));
typedef __attribute__((ext_vector_type(4))) float f32x4;
typedef __attribute__((ext_vector_type(4))) unsigned int uint4v;
typedef __attribute__((ext_vector_type(2))) unsigned int uint2v;

#define B_   8
#define LX_  2048
#define LY_  2048
#define D_   256
#define NROW (B_ * LX_)   // 16384
#define MTOT (2 * NROW)   // 32768 combined x+y rows

__device__ __forceinline__ unsigned short f2bf(float f) {
  unsigned u = __builtin_bit_cast(unsigned, f);
  u += 0x7FFF + ((u >> 16) & 1);          // RNE truncate (inputs are finite)
  return (unsigned short)(u >> 16);
}
__device__ __forceinline__ float bf2f(unsigned short h) {
  unsigned u = ((unsigned)h) << 16;
  return __builtin_bit_cast(float, u);
}

// ---------------- prep: blocks 0..7 mask scan; blocks 8..39 W split ---
__global__ __launch_bounds__(256) void prep_kernel(
    const float* __restrict__ W, unsigned short* __restrict__ Whi,
    unsigned short* __restrict__ Wlo,
    const int* __restrict__ MASK, int* __restrict__ CIDX,
    int* __restrict__ CPOS, int* __restrict__ Lc) {
  int t = threadIdx.x;
  if (blockIdx.x >= 8) {
    // W -> hi/lo bf16 split: 32 blocks x 2048 elems
    int base = (blockIdx.x - 8) * 2048 + t * 8;
    f32x4 f0 = *(const f32x4*)(W + base);
    f32x4 f1 = *(const f32x4*)(W + base + 4);
    float v[8] = {f0[0], f0[1], f0[2], f0[3], f1[0], f1[1], f1[2], f1[3]};
    unsigned short h[8], l[8];
    for (int j = 0; j < 8; ++j) {
      h[j] = f2bf(v[j]);
      l[j] = f2bf(v[j] - bf2f(h[j]));
    }
    uint4v vh = {(unsigned)h[0] | ((unsigned)h[1] << 16), (unsigned)h[2] | ((unsigned)h[3] << 16),
                 (unsigned)h[4] | ((unsigned)h[5] << 16), (unsigned)h[6] | ((unsigned)h[7] << 16)};
    uint4v vl = {(unsigned)l[0] | ((unsigned)l[1] << 16), (unsigned)l[2] | ((unsigned)l[3] << 16),
                 (unsigned)l[4] | ((unsigned)l[5] << 16), (unsigned)l[6] | ((unsigned)l[7] << 16)};
    *(uint4v*)(Whi + base) = vh;
    *(uint4v*)(Wlo + base) = vl;
    return;
  }
  // per-batch compaction scan (keep j where mask==0)
  __shared__ int s[256];
  int b = blockIdx.x;
  int f[8];
  int cnt = 0;
  for (int k = 0; k < 8; ++k) {
    f[k] = (MASK[b * 2048 + t * 8 + k] == 0) ? 1 : 0;
    cnt += f[k];
  }
  s[t] = cnt;
  __syncthreads();
  for (int off = 1; off < 256; off <<= 1) {   // Hillis-Steele inclusive scan
    int v = (t >= off) ? s[t - off] : 0;
    __syncthreads();
    s[t] += v;
    __syncthreads();
  }
  if (t == 255) Lc[b] = s[255];
  int off = s[t] - cnt;
  for (int k = 0; k < 8; ++k) {
    int j = t * 8 + k;
    if (f[k]) {
      CIDX[b * 2048 + off] = j;
      CPOS[b * 2048 + j] = b * 2048 + off;
      ++off;
    } else {
      CPOS[b * 2048 + j] = -1;
    }
  }
}

// ---------------- x,y fp32 -> bf16 hi/lo (rows 0..16383 x, then y) ----
// 4096 blocks: 2048 per input, 2048 elements per block.
__global__ __launch_bounds__(256) void split_xy_kernel(
    const float* __restrict__ X, const float* __restrict__ Y,
    unsigned short* __restrict__ XYhi, unsigned short* __restrict__ XYlo) {
  int bb = blockIdx.x;
  const float* src;
  size_t off;
  if (bb < 2048) { src = X; off = 0; }
  else           { src = Y; off = (size_t)NROW * D_; bb -= 2048; }
  size_t e0 = ((size_t)bb * 256 + threadIdx.x) * 8;
  f32x4 f0 = *(const f32x4*)(src + e0);
  f32x4 f1 = *(const f32x4*)(src + e0 + 4);
  float v[8] = {f0[0], f0[1], f0[2], f0[3], f1[0], f1[1], f1[2], f1[3]};
  unsigned short h[8], l[8];
  for (int j = 0; j < 8; ++j) {
    h[j] = f2bf(v[j]);
    l[j] = f2bf(v[j] - bf2f(h[j]));
  }
  uint4v vh = {(unsigned)h[0] | ((unsigned)h[1] << 16), (unsigned)h[2] | ((unsigned)h[3] << 16),
               (unsigned)h[4] | ((unsigned)h[5] << 16), (unsigned)h[6] | ((unsigned)h[7] << 16)};
  uint4v vl = {(unsigned)l[0] | ((unsigned)l[1] << 16), (unsigned)l[2] | ((unsigned)l[3] << 16),
               (unsigned)l[4] | ((unsigned)l[5] << 16), (unsigned)l[6] | ((unsigned)l[7] << 16)};
  *(uint4v*)(XYhi + off + e0) = vh;
  *(uint4v*)(XYlo + off + e0) = vl;
}

// ---------------- proj = relu(in @ W^T + b), exact via bf16 hi/lo split
// Pre-split A inputs: staging is pure copy. Register-prefetch pipeline.
// 512 blocks x 64 rows (rows 0..16383 -> XP; 16384.. -> YPc scattered).
__global__ __launch_bounds__(256, 2) void proj_kernel(
    const unsigned short* __restrict__ XYhi, const unsigned short* __restrict__ XYlo,
    const float* __restrict__ bias,
    const unsigned short* __restrict__ Whi, const unsigned short* __restrict__ Wlo,
    const int* __restrict__ CPOS,
    _Float16* __restrict__ XP, _Float16* __restrict__ YPc) {
  __shared__ unsigned short Ah[64][40], Al[64][40];
  __shared__ unsigned short Bh[256][40], Bl[256][40];

  int t = threadIdx.x;
  int lane = t & 63, wave = t >> 6;
  int q = lane >> 4, n15 = lane & 15;

  bool isX = blockIdx.x < 256;
  int m0 = blockIdx.x * 64;                 // global row over combined 32768

  f32x4 acc[4][4];
  for (int mt = 0; mt < 4; ++mt)
    for (int nt = 0; nt < 4; ++nt) acc[mt][nt] = (f32x4){0.f, 0.f, 0.f, 0.f};

  int arow = t >> 2, aseg = t & 3;          // 64 rows x 4 segs of 8 bf16
  int erow = t >> 2, ec = t & 3;

  uint4v pah, pal, pbh[4], pbl[4];
#define PROJ_PF(kc)                                                            \
  {                                                                            \
    size_t aoff = (size_t)(m0 + arow) * D_ + (kc) * 32 + aseg * 8;             \
    pah = *(const uint4v*)(XYhi + aoff);                                       \
    pal = *(const uint4v*)(XYlo + aoff);                                       \
    for (int p = 0; p < 4; ++p) {                                              \
      int e = p * 64 + erow;                                                   \
      pbh[p] = *(const uint4v*)(Whi + (size_t)e * D_ + (kc) * 32 + ec * 8);    \
      pbl[p] = *(const uint4v*)(Wlo + (size_t)e * D_ + (kc) * 32 + ec * 8);    \
    }                                                                          \
  }

  PROJ_PF(0);

  for (int kc = 0; kc < 8; ++kc) {
    __syncthreads();     // previous chunk's consumers done
    *(uint4v*)&Ah[arow][aseg * 8] = pah;
    *(uint4v*)&Al[arow][aseg * 8] = pal;
    for (int p = 0; p < 4; ++p) {
      int e = p * 64 + erow;
      *(uint4v*)&Bh[e][ec * 8] = pbh[p];
      *(uint4v*)&Bl[e][ec * 8] = pbl[p];
    }
    if (kc < 7) PROJ_PF(kc + 1);    // lands during MFMA section
    __syncthreads();

    short8 afh[4], afl[4], bfh[4], bfl[4];
    for (int mt = 0; mt < 4; ++mt) {
      afh[mt] = *(const short8*)&Ah[mt * 16 + n15][q * 8];
      afl[mt] = *(const short8*)&Al[mt * 16 + n15][q * 8];
    }
    for (int nt = 0; nt < 4; ++nt) {
      bfh[nt] = *(const short8*)&Bh[wave * 64 + nt * 16 + n15][q * 8];
      bfl[nt] = *(const short8*)&Bl[wave * 64 + nt * 16 + n15][q * 8];
    }
    for (int mt = 0; mt < 4; ++mt)
      for (int nt = 0; nt < 4; ++nt) {
        acc[mt][nt] = __builtin_amdgcn_mfma_f32_16x16x32_bf16(afh[mt], bfh[nt], acc[mt][nt], 0, 0, 0);
        acc[mt][nt] = __builtin_amdgcn_mfma_f32_16x16x32_bf16(afl[mt], bfh[nt], acc[mt][nt], 0, 0, 0);
        acc[mt][nt] = __builtin_amdgcn_mfma_f32_16x16x32_bf16(afh[mt], bfl[nt], acc[mt][nt], 0, 0, 0);
      }
  }
#undef PROJ_PF

  // epilogue: bias + relu + fp16 store (X direct, Y scattered-compact)
  int drow[16];
  for (int mt = 0; mt < 4; ++mt)
    for (int r = 0; r < 4; ++r) {
      int row = m0 + mt * 16 + q * 4 + r;
      drow[mt * 4 + r] = isX ? row : CPOS[row - NROW];
    }
  _Float16* dst = isX ? XP : YPc;
  for (int nt = 0; nt < 4; ++nt) {
    int e = wave * 64 + nt * 16 + n15;
    float bv = bias[e];
    for (int mt = 0; mt < 4; ++mt)
      for (int r = 0; r < 4; ++r) {
        int dr = drow[mt * 4 + r];
        if (dr >= 0) {
          float v = acc[mt][nt][r] + bv;
          v = v > 0.f ? v : 0.f;
          dst[(size_t)dr * D_ + e] = (_Float16)v;
        }
      }
  }
}

// ---------------- gather+transpose raw y -> YTc fp16 [B][D][j] --------
__global__ __launch_bounds__(256) void gatherT_kernel(
    const float* __restrict__ Y, const int* __restrict__ CIDX,
    const int* __restrict__ Lc, _Float16* __restrict__ YTc) {
  __shared__ _Float16 tile[64][72];
  int id = blockIdx.x;
  int db = id & 3, nb = (id >> 2) & 31, b = id >> 7;
  int lc = Lc[b];
  int end = (lc + 31) & ~31;
  if (nb * 64 >= end) return;              // rows never read by flash
  int t = threadIdx.x;
  int nl = t >> 2, ds = t & 3;
  int j = nb * 64 + nl;
  int idx = (j < lc) ? CIDX[b * 2048 + j] : 0;
  const float* src = Y + (size_t)(b * LY_ + idx) * D_ + db * 64 + ds * 16;
  for (int i = 0; i < 4; ++i) {
    f32x4 f = *(const f32x4*)(src + i * 4);
    for (int k = 0; k < 4; ++k) tile[ds * 16 + i * 4 + k][nl] = (_Float16)f[k];
  }
  __syncthreads();
  int dl = t >> 2, nsub = t & 3;
  uint4v v0 = *(const uint4v*)&tile[dl][nsub * 16];
  uint4v v1 = *(const uint4v*)&tile[dl][nsub * 16 + 8];
  _Float16* dst = YTc + (size_t)(b * D_ + db * 64 + dl) * LY_ + nb * 64 + nsub * 16;
  *(uint4v*)(dst) = v0;
  *(uint4v*)(dst + 8) = v1;
}

// ---------------- flash attention over COMPACTED y, split halves ------
// grid 512: (b, 64 x-rows, tile-half). 4 waves x 16 rows. tiles of 32 j.
__global__ __launch_bounds__(256, 2) void flash_kernel(
    const _Float16* __restrict__ XP, const _Float16* __restrict__ YPc,
    const _Float16* __restrict__ YTc, const int* __restrict__ Lc,
    _Float16* __restrict__ PO, float* __restrict__ Pm, float* __restrict__ Pl) {
  __shared__ _Float16 yp_t[32][264];   // [j][d], +8 pad (row 528 B)
  __shared__ _Float16 yT_t[256][40];   // [d][j], +8 pad (row 80 B)
  __shared__ _Float16 pbuf[4][16][40]; // per-wave P round-trip

  int t = threadIdx.x;
  int lane = t & 63, wave = t >> 6;
  int q = lane >> 4, n15 = lane & 15;
  int half = blockIdx.x & 1;
  int xb = (blockIdx.x >> 1) & 31;
  int b = blockIdx.x >> 6;
  int row0 = xb * 64 + wave * 16;

  int lc = Lc[b];
  int T  = (lc + 31) >> 5;
  int T0 = (T + 1) >> 1;
  int tstart = half ? T0 : 0;
  int tend   = half ? T  : T0;

  half8 a[8];
  const _Float16* xrow = XP + (size_t)(b * LX_ + row0 + n15) * D_ + q * 8;
  for (int kk = 0; kk < 8; ++kk) a[kk] = *(const half8*)(xrow + kk * 32);

  half8 lones;
  for (int j = 0; j < 8; ++j) lones[j] = (n15 == 0) ? (_Float16)1 : (_Float16)0;

  float m_r[4];
  for (int r = 0; r < 4; ++r) m_r[r] = -1e30f;
  f32x4 lacc = {0.f, 0.f, 0.f, 0.f};
  f32x4 oacc[16];
  for (int dt = 0; dt < 16; ++dt) oacc[dt] = (f32x4){0.f, 0.f, 0.f, 0.f};

  const _Float16* ypb = YPc + (size_t)b * LY_ * D_;
  const _Float16* yTb = YTc + (size_t)b * D_ * LY_;

  uint4v pr[8];
#define PREFETCH(tt)                                                          \
  {                                                                           \
    int y0p = (tt) * 32;                                                      \
    for (int i = 0; i < 4; ++i) {                                             \
      int c = t + i * 256;                                                    \
      pr[i] = *(const uint4v*)(ypb + (size_t)(y0p + (c >> 5)) * D_ + (c & 31) * 8); \
    }                                                                         \
    for (int i = 0; i < 4; ++i) {                                             \
      int c = t + i * 256;                                                    \
      pr[4 + i] = *(const uint4v*)(yTb + (size_t)(c >> 2) * LY_ + y0p + (c & 3) * 8); \
    }                                                                         \
  }

  if (tstart < tend) PREFETCH(tstart);

  for (int tt = tstart; tt < tend; ++tt) {
    int y0 = tt * 32;
    __syncthreads();
    for (int i = 0; i < 4; ++i) {
      int c = t + i * 256;
      *(uint4v*)&yp_t[c >> 5][(c & 31) * 8] = pr[i];
    }
    for (int i = 0; i < 4; ++i) {
      int c = t + i * 256;
      *(uint4v*)&yT_t[c >> 2][(c & 3) * 8] = pr[4 + i];
    }
    if (tt + 1 < tend) PREFETCH(tt + 1);
    __syncthreads();

    f32x4 S0 = {0.f, 0.f, 0.f, 0.f}, S1 = {0.f, 0.f, 0.f, 0.f};
    for (int kk = 0; kk < 8; ++kk) {
      half8 b0 = *(const half8*)&yp_t[n15][kk * 32 + q * 8];
      S0 = __builtin_amdgcn_mfma_f32_16x16x32_f16(a[kk], b0, S0, 0, 0, 0);
    }
    for (int kk = 0; kk < 8; ++kk) {
      half8 b1 = *(const half8*)&yp_t[16 + n15][kk * 32 + q * 8];
      S1 = __builtin_amdgcn_mfma_f32_16x16x32_f16(a[kk], b1, S1, 0, 0, 0);
    }
    bool mk0 = (y0 + n15) >= lc;
    bool mk1 = (y0 + 16 + n15) >= lc;

    float al[4];
    _Float16 ph0[4], ph1[4];
    bool need = false;
    for (int r = 0; r < 4; ++r) {
      float s0 = mk0 ? -1e30f : S0[r];
      float s1 = mk1 ? -1e30f : S1[r];
      float tm = fmaxf(s0, s1);
      tm = fmaxf(tm, __shfl_xor(tm, 1));
      tm = fmaxf(tm, __shfl_xor(tm, 2));
      tm = fmaxf(tm, __shfl_xor(tm, 4));
      tm = fmaxf(tm, __shfl_xor(tm, 8));
      float mn = fmaxf(m_r[r], tm);
      al[r] = __expf(m_r[r] - mn);
      m_r[r] = mn;
      ph0[r] = (_Float16)__expf(s0 - mn);
      ph1[r] = (_Float16)__expf(s1 - mn);
      need = need || (al[r] != 1.0f);
    }
    if (__ballot(need)) {
      for (int dt = 0; dt < 16; ++dt)
        for (int r = 0; r < 4; ++r) oacc[dt][r] *= al[r];
      for (int r = 0; r < 4; ++r) lacc[r] *= al[r];
    }
    for (int r = 0; r < 4; ++r) {
      pbuf[wave][q * 4 + r][n15] = ph0[r];
      pbuf[wave][q * 4 + r][16 + n15] = ph1[r];
    }
    half8 pa = *(const half8*)&pbuf[wave][n15][q * 8];
    lacc = __builtin_amdgcn_mfma_f32_16x16x32_f16(pa, lones, lacc, 0, 0, 0);
    for (int dt = 0; dt < 16; ++dt) {
      half8 bb = *(const half8*)&yT_t[dt * 16 + n15][q * 8];
      oacc[dt] = __builtin_amdgcn_mfma_f32_16x16x32_f16(pa, bb, oacc[dt], 0, 0, 0);
    }
  }
#undef PREFETCH

  size_t prow = (size_t)(half * B_ + b) * LX_ + row0;
  _Float16* po = PO + prow * D_;
  for (int dt = 0; dt < 16; ++dt)
    for (int r = 0; r < 4; ++r)
      po[(size_t)(q * 4 + r) * D_ + dt * 16 + n15] = (_Float16)oacc[dt][r];
  if (n15 == 0) {
    for (int r = 0; r < 4; ++r) {
      Pm[prow + q * 4 + r] = m_r[r];
      Pl[prow + q * 4 + r] = lacc[r];
    }
  }
}

// ---------------- merge the two tile-half partials --------------------
__global__ __launch_bounds__(256) void merge_kernel(
    const _Float16* __restrict__ PO, const float* __restrict__ Pm,
    const float* __restrict__ Pl, float* __restrict__ OUT) {
  int c = blockIdx.x * 256 + threadIdx.x;
  int row = c >> 5, seg = c & 31;
  float m0 = Pm[row], m1 = Pm[NROW + row];
  float l0 = Pl[row], l1 = Pl[NROW + row];
  float m = fmaxf(m0, m1);
  float w0 = __expf(m0 - m), w1 = __expf(m1 - m);
  float inv = 1.0f / (l0 * w0 + l1 * w1);
  const _Float16* p0 = PO + (size_t)row * D_ + seg * 8;
  const _Float16* p1 = p0 + (size_t)NROW * D_;
  half8 a = *(const half8*)p0;
  half8 bsec = *(const half8*)p1;
  float* o = OUT + (size_t)row * D_ + seg * 8;
  f32x4 o0, o1;
  for (int j = 0; j < 4; ++j) o0[j] = ((float)a[j] * w0 + (float)bsec[j] * w1) * inv;
  for (int j = 0; j < 4; ++j) o1[j] = ((float)a[4 + j] * w0 + (float)bsec[4 + j] * w1) * inv;
  *(f32x4*)o = o0;
  *(f32x4*)(o + 4) = o1;
}

extern "C" void kernel_launch(void* const* d_in, const int* in_sizes, int n_in,
                              void* d_out, int out_size, void* d_ws, size_t ws_size,
                              hipStream_t stream) {
  const float* x     = (const float*)d_in[0];  // [8,2048,256]
  const float* y     = (const float*)d_in[1];  // [8,2048,256]
  const int*   ymask = (const int*)  d_in[2];  // [8,2048]
  const float* W     = (const float*)d_in[3];  // [256,256]
  const float* bias  = (const float*)d_in[4];  // [256]
  float* out = (float*)d_out;

  // ws layout (~57 MB; PO aliases XYhi, which is dead after proj)
  char* ws = (char*)d_ws;
  size_t o = 0;
  unsigned short* Whi  = (unsigned short*)(ws + o); o += 131072;
  unsigned short* Wlo  = (unsigned short*)(ws + o); o += 131072;
  unsigned short* XYhi = (unsigned short*)(ws + o);
  _Float16*       PO   = (_Float16*)(ws + o);       o += (size_t)MTOT * D_ * 2;  // 16 MB
  unsigned short* XYlo = (unsigned short*)(ws + o); o += (size_t)MTOT * D_ * 2;  // 16 MB
  _Float16* XP  = (_Float16*)(ws + o); o += 8388608;
  _Float16* YPc = (_Float16*)(ws + o); o += 8388608;
  _Float16* YTc = (_Float16*)(ws + o); o += 8388608;
  float* Pm   = (float*)(ws + o); o += 131072;
  float* Pl   = (float*)(ws + o); o += 131072;
  int*   CIDX = (int*)  (ws + o); o += 65536;
  int*   CPOS = (int*)  (ws + o); o += 65536;
  int*   Lc   = (int*)  (ws + o);

  prep_kernel<<<40, 256, 0, stream>>>(W, Whi, Wlo, ymask, CIDX, CPOS, Lc);
  split_xy_kernel<<<4096, 256, 0, stream>>>(x, y, XYhi, XYlo);
  proj_kernel<<<512, 256, 0, stream>>>(XYhi, XYlo, bias, Whi, Wlo, CPOS, XP, YPc);
  gatherT_kernel<<<1024, 256, 0, stream>>>(y, CIDX, Lc, YTc);
  flash_kernel<<<512, 256, 0, stream>>>(XP, YPc, YTc, Lc, PO, Pm, Pl);
  merge_kernel<<<2048, 256, 0, stream>>>(PO, Pm, Pl, out);
}

// Round 10
// 165.484 us; speedup vs baseline: 1.0399x; 1.0399x over previous
//
#include <hip/hip_runtime.h>

typedef __attribute__((ext_vector_type(8))) short short8;
typedef _Float16 half8 __attribute__((ext_vector_type(8)));
typedef __attribute__((ext_vector_type(4))) float f32x4;
typedef __attribute__((ext_vector_type(4))) unsigned int uint4v;
typedef __attribute__((ext_vector_type(2))) unsigned int uint2v;

#define B_   8
#define LX_  2048
#define LY_  2048
#define D_   256
#define NROW (B_ * LX_)   // 16384
#define NQ   4            // LY quarters in flash

__device__ __forceinline__ unsigned short f2bf(float f) {
  unsigned u = __builtin_bit_cast(unsigned, f);
  u += 0x7FFF + ((u >> 16) & 1);          // RNE truncate (inputs are finite)
  return (unsigned short)(u >> 16);
}
__device__ __forceinline__ float bf2f(unsigned short h) {
  unsigned u = ((unsigned)h) << 16;
  return __builtin_bit_cast(float, u);
}

// ---------------- prep: blocks 0..7 mask scan; blocks 8..39 W split ---
__global__ __launch_bounds__(256) void prep_kernel(
    const float* __restrict__ W, unsigned short* __restrict__ Whi,
    unsigned short* __restrict__ Wlo,
    const int* __restrict__ MASK, int* __restrict__ CIDX,
    int* __restrict__ CPOS, int* __restrict__ Lc) {
  int t = threadIdx.x;
  if (blockIdx.x >= 8) {
    int base = (blockIdx.x - 8) * 2048 + t * 8;
    f32x4 f0 = *(const f32x4*)(W + base);
    f32x4 f1 = *(const f32x4*)(W + base + 4);
    float v[8] = {f0[0], f0[1], f0[2], f0[3], f1[0], f1[1], f1[2], f1[3]};
    unsigned short h[8], l[8];
    for (int j = 0; j < 8; ++j) {
      h[j] = f2bf(v[j]);
      l[j] = f2bf(v[j] - bf2f(h[j]));
    }
    uint4v vh = {(unsigned)h[0] | ((unsigned)h[1] << 16), (unsigned)h[2] | ((unsigned)h[3] << 16),
                 (unsigned)h[4] | ((unsigned)h[5] << 16), (unsigned)h[6] | ((unsigned)h[7] << 16)};
    uint4v vl = {(unsigned)l[0] | ((unsigned)l[1] << 16), (unsigned)l[2] | ((unsigned)l[3] << 16),
                 (unsigned)l[4] | ((unsigned)l[5] << 16), (unsigned)l[6] | ((unsigned)l[7] << 16)};
    *(uint4v*)(Whi + base) = vh;
    *(uint4v*)(Wlo + base) = vl;
    return;
  }
  __shared__ int s[256];
  int b = blockIdx.x;
  int f[8];
  int cnt = 0;
  for (int k = 0; k < 8; ++k) {
    f[k] = (MASK[b * 2048 + t * 8 + k] == 0) ? 1 : 0;
    cnt += f[k];
  }
  s[t] = cnt;
  __syncthreads();
  for (int off = 1; off < 256; off <<= 1) {
    int v = (t >= off) ? s[t - off] : 0;
    __syncthreads();
    s[t] += v;
    __syncthreads();
  }
  if (t == 255) Lc[b] = s[255];
  int off = s[t] - cnt;
  for (int k = 0; k < 8; ++k) {
    int j = t * 8 + k;
    if (f[k]) {
      CIDX[b * 2048 + off] = j;
      CPOS[b * 2048 + j] = b * 2048 + off;
      ++off;
    } else {
      CPOS[b * 2048 + j] = -1;
    }
  }
}

// ---------------- fused: blocks 0..511 proj ; 512..1535 gatherT -------
// proj: relu(in @ W^T + b) exact via bf16 hi/lo split, inline A-split,
//       register prefetch. X rows -> XP, Y rows -> YPc (scatter-compact).
// gatherT: compacted y gather + transpose -> YTc fp16 [B][D][j].
__global__ __launch_bounds__(256, 2) void projgather_kernel(
    const float* __restrict__ X, const float* __restrict__ Y,
    const float* __restrict__ bias,
    const unsigned short* __restrict__ Whi, const unsigned short* __restrict__ Wlo,
    const int* __restrict__ CPOS, const int* __restrict__ CIDX,
    const int* __restrict__ Lc,
    _Float16* __restrict__ XP, _Float16* __restrict__ YPc,
    _Float16* __restrict__ YTc) {
  __shared__ __align__(16) unsigned char smem[51200];
  int t = threadIdx.x;

  if (blockIdx.x >= 512) {
    // ---------------- gatherT ----------------
    _Float16 (*tile)[72] = (_Float16(*)[72])smem;   // 9216 B of smem
    int id = blockIdx.x - 512;
    int db = id & 3, nb = (id >> 2) & 31, b = id >> 7;
    int lc = Lc[b];
    int end = (lc + 31) & ~31;
    if (nb * 64 >= end) return;            // rows never read by flash
    int nl = t >> 2, ds = t & 3;
    int j = nb * 64 + nl;
    int idx = (j < lc) ? CIDX[b * 2048 + j] : 0;
    const float* src = Y + (size_t)(b * LY_ + idx) * D_ + db * 64 + ds * 16;
    for (int i = 0; i < 4; ++i) {
      f32x4 f = *(const f32x4*)(src + i * 4);
      for (int k = 0; k < 4; ++k) tile[ds * 16 + i * 4 + k][nl] = (_Float16)f[k];
    }
    __syncthreads();
    int dl = t >> 2, nsub = t & 3;
    uint4v v0 = *(const uint4v*)&tile[dl][nsub * 16];
    uint4v v1 = *(const uint4v*)&tile[dl][nsub * 16 + 8];
    _Float16* dst = YTc + (size_t)(b * D_ + db * 64 + dl) * LY_ + nb * 64 + nsub * 16;
    *(uint4v*)(dst) = v0;
    *(uint4v*)(dst + 8) = v1;
    return;
  }

  // ---------------- proj ----------------
  unsigned short (*Ah)[40] = (unsigned short(*)[40])(smem);           // 5120
  unsigned short (*Al)[40] = (unsigned short(*)[40])(smem + 5120);    // 5120
  unsigned short (*Bh)[40] = (unsigned short(*)[40])(smem + 10240);   // 20480
  unsigned short (*Bl)[40] = (unsigned short(*)[40])(smem + 30720);   // 20480

  int lane = t & 63, wave = t >> 6;
  int q = lane >> 4, n15 = lane & 15;

  bool isX = blockIdx.x < 256;
  const float* src = isX ? X : Y;
  int m0 = (isX ? blockIdx.x : (blockIdx.x - 256)) * 64;

  f32x4 acc[4][4];
  for (int mt = 0; mt < 4; ++mt)
    for (int nt = 0; nt < 4; ++nt) acc[mt][nt] = (f32x4){0.f, 0.f, 0.f, 0.f};

  int arow = t >> 2, aseg = t & 3;
  int erow = t >> 2, ec = t & 3;

  f32x4 pa[2];
  uint4v pbh[4], pbl[4];
#define PROJ_PF(kc)                                                            \
  {                                                                            \
    for (int i = 0; i < 2; ++i)                                                \
      pa[i] = *(const f32x4*)(src + (size_t)(m0 + arow) * D_ + (kc) * 32 +     \
                              (aseg + i * 4) * 4);                             \
    for (int p = 0; p < 4; ++p) {                                              \
      int e = p * 64 + erow;                                                   \
      pbh[p] = *(const uint4v*)(Whi + (size_t)e * D_ + (kc) * 32 + ec * 8);    \
      pbl[p] = *(const uint4v*)(Wlo + (size_t)e * D_ + (kc) * 32 + ec * 8);    \
    }                                                                          \
  }

  PROJ_PF(0);

  for (int kc = 0; kc < 8; ++kc) {
    __syncthreads();
    for (int i = 0; i < 2; ++i) {
      int seg = aseg + i * 4;
      f32x4 f = pa[i];
      unsigned short h[4], l[4];
      for (int j = 0; j < 4; ++j) {
        h[j] = f2bf(f[j]);
        l[j] = f2bf(f[j] - bf2f(h[j]));
      }
      uint2v vh = {(unsigned)h[0] | ((unsigned)h[1] << 16),
                   (unsigned)h[2] | ((unsigned)h[3] << 16)};
      uint2v vl = {(unsigned)l[0] | ((unsigned)l[1] << 16),
                   (unsigned)l[2] | ((unsigned)l[3] << 16)};
      *(uint2v*)&Ah[arow][seg * 4] = vh;
      *(uint2v*)&Al[arow][seg * 4] = vl;
    }
    for (int p = 0; p < 4; ++p) {
      int e = p * 64 + erow;
      *(uint4v*)&Bh[e][ec * 8] = pbh[p];
      *(uint4v*)&Bl[e][ec * 8] = pbl[p];
    }
    if (kc < 7) PROJ_PF(kc + 1);
    __syncthreads();

    short8 afh[4], afl[4], bfh[4], bfl[4];
    for (int mt = 0; mt < 4; ++mt) {
      afh[mt] = *(const short8*)&Ah[mt * 16 + n15][q * 8];
      afl[mt] = *(const short8*)&Al[mt * 16 + n15][q * 8];
    }
    for (int nt = 0; nt < 4; ++nt) {
      bfh[nt] = *(const short8*)&Bh[wave * 64 + nt * 16 + n15][q * 8];
      bfl[nt] = *(const short8*)&Bl[wave * 64 + nt * 16 + n15][q * 8];
    }
    for (int mt = 0; mt < 4; ++mt)
      for (int nt = 0; nt < 4; ++nt) {
        acc[mt][nt] = __builtin_amdgcn_mfma_f32_16x16x32_bf16(afh[mt], bfh[nt], acc[mt][nt], 0, 0, 0);
        acc[mt][nt] = __builtin_amdgcn_mfma_f32_16x16x32_bf16(afl[mt], bfh[nt], acc[mt][nt], 0, 0, 0);
        acc[mt][nt] = __builtin_amdgcn_mfma_f32_16x16x32_bf16(afh[mt], bfl[nt], acc[mt][nt], 0, 0, 0);
      }
  }
#undef PROJ_PF

  int drow[16];
  for (int mt = 0; mt < 4; ++mt)
    for (int r = 0; r < 4; ++r) {
      int row = m0 + mt * 16 + q * 4 + r;
      drow[mt * 4 + r] = isX ? row : CPOS[row];
    }
  _Float16* dst = isX ? XP : YPc;
  for (int nt = 0; nt < 4; ++nt) {
    int e = wave * 64 + nt * 16 + n15;
    float bv = bias[e];
    for (int mt = 0; mt < 4; ++mt)
      for (int r = 0; r < 4; ++r) {
        int dr = drow[mt * 4 + r];
        if (dr >= 0) {
          float v = acc[mt][nt][r] + bv;
          v = v > 0.f ? v : 0.f;
          dst[(size_t)dr * D_ + e] = (_Float16)v;
        }
      }
  }
}

// ---------------- flash attention over COMPACTED y, LY-quarters -------
// grid 1024: (b, 64 x-rows, quarter). 4 waves x 16 rows. tiles of 32 j.
__global__ __launch_bounds__(256, 2) void flash_kernel(
    const _Float16* __restrict__ XP, const _Float16* __restrict__ YPc,
    const _Float16* __restrict__ YTc, const int* __restrict__ Lc,
    _Float16* __restrict__ PO, float* __restrict__ Pm, float* __restrict__ Pl) {
  __shared__ _Float16 yp_t[32][264];   // [j][d], +8 pad
  __shared__ _Float16 yT_t[256][40];   // [d][j], +8 pad
  __shared__ _Float16 pbuf[4][16][40]; // per-wave P round-trip

  int t = threadIdx.x;
  int lane = t & 63, wave = t >> 6;
  int q = lane >> 4, n15 = lane & 15;
  int qtr = blockIdx.x & 3;
  int xb = (blockIdx.x >> 2) & 31;
  int b = blockIdx.x >> 7;
  int row0 = xb * 64 + wave * 16;

  int lc = Lc[b];
  int T = (lc + 31) >> 5;
  int tstart = (T * qtr) >> 2;
  int tend   = (T * (qtr + 1)) >> 2;

  half8 a[8];
  const _Float16* xrow = XP + (size_t)(b * LX_ + row0 + n15) * D_ + q * 8;
  for (int kk = 0; kk < 8; ++kk) a[kk] = *(const half8*)(xrow + kk * 32);

  half8 lones;
  for (int j = 0; j < 8; ++j) lones[j] = (n15 == 0) ? (_Float16)1 : (_Float16)0;

  float m_r[4];
  for (int r = 0; r < 4; ++r) m_r[r] = -1e30f;
  f32x4 lacc = {0.f, 0.f, 0.f, 0.f};
  f32x4 oacc[16];
  for (int dt = 0; dt < 16; ++dt) oacc[dt] = (f32x4){0.f, 0.f, 0.f, 0.f};

  const _Float16* ypb = YPc + (size_t)b * LY_ * D_;
  const _Float16* yTb = YTc + (size_t)b * D_ * LY_;

  uint4v pr[8];
#define PREFETCH(tt)                                                          \
  {                                                                           \
    int y0p = (tt) * 32;                                                      \
    for (int i = 0; i < 4; ++i) {                                             \
      int c = t + i * 256;                                                    \
      pr[i] = *(const uint4v*)(ypb + (size_t)(y0p + (c >> 5)) * D_ + (c & 31) * 8); \
    }                                                                         \
    for (int i = 0; i < 4; ++i) {                                             \
      int c = t + i * 256;                                                    \
      pr[4 + i] = *(const uint4v*)(yTb + (size_t)(c >> 2) * LY_ + y0p + (c & 3) * 8); \
    }                                                                         \
  }

  if (tstart < tend) PREFETCH(tstart);

  for (int tt = tstart; tt < tend; ++tt) {
    int y0 = tt * 32;
    __syncthreads();
    for (int i = 0; i < 4; ++i) {
      int c = t + i * 256;
      *(uint4v*)&yp_t[c >> 5][(c & 31) * 8] = pr[i];
    }
    for (int i = 0; i < 4; ++i) {
      int c = t + i * 256;
      *(uint4v*)&yT_t[c >> 2][(c & 3) * 8] = pr[4 + i];
    }
    if (tt + 1 < tend) PREFETCH(tt + 1);
    __syncthreads();

    f32x4 S0 = {0.f, 0.f, 0.f, 0.f}, S1 = {0.f, 0.f, 0.f, 0.f};
    for (int kk = 0; kk < 8; ++kk) {
      half8 b0 = *(const half8*)&yp_t[n15][kk * 32 + q * 8];
      S0 = __builtin_amdgcn_mfma_f32_16x16x32_f16(a[kk], b0, S0, 0, 0, 0);
    }
    for (int kk = 0; kk < 8; ++kk) {
      half8 b1 = *(const half8*)&yp_t[16 + n15][kk * 32 + q * 8];
      S1 = __builtin_amdgcn_mfma_f32_16x16x32_f16(a[kk], b1, S1, 0, 0, 0);
    }
    bool mk0 = (y0 + n15) >= lc;
    bool mk1 = (y0 + 16 + n15) >= lc;

    float al[4];
    _Float16 ph0[4], ph1[4];
    bool need = false;
    for (int r = 0; r < 4; ++r) {
      float s0 = mk0 ? -1e30f : S0[r];
      float s1 = mk1 ? -1e30f : S1[r];
      float tm = fmaxf(s0, s1);
      tm = fmaxf(tm, __shfl_xor(tm, 1));
      tm = fmaxf(tm, __shfl_xor(tm, 2));
      tm = fmaxf(tm, __shfl_xor(tm, 4));
      tm = fmaxf(tm, __shfl_xor(tm, 8));
      float mn = fmaxf(m_r[r], tm);
      al[r] = __expf(m_r[r] - mn);
      m_r[r] = mn;
      ph0[r] = (_Float16)__expf(s0 - mn);
      ph1[r] = (_Float16)__expf(s1 - mn);
      need = need || (al[r] != 1.0f);
    }
    if (__ballot(need)) {
      for (int dt = 0; dt < 16; ++dt)
        for (int r = 0; r < 4; ++r) oacc[dt][r] *= al[r];
      for (int r = 0; r < 4; ++r) lacc[r] *= al[r];
    }
    for (int r = 0; r < 4; ++r) {
      pbuf[wave][q * 4 + r][n15] = ph0[r];
      pbuf[wave][q * 4 + r][16 + n15] = ph1[r];
    }
    half8 pa = *(const half8*)&pbuf[wave][n15][q * 8];
    lacc = __builtin_amdgcn_mfma_f32_16x16x32_f16(pa, lones, lacc, 0, 0, 0);
    for (int dt = 0; dt < 16; ++dt) {
      half8 bb = *(const half8*)&yT_t[dt * 16 + n15][q * 8];
      oacc[dt] = __builtin_amdgcn_mfma_f32_16x16x32_f16(pa, bb, oacc[dt], 0, 0, 0);
    }
  }
#undef PREFETCH

  size_t prow = (size_t)(qtr * B_ + b) * LX_ + row0;
  _Float16* po = PO + prow * D_;
  for (int dt = 0; dt < 16; ++dt)
    for (int r = 0; r < 4; ++r)
      po[(size_t)(q * 4 + r) * D_ + dt * 16 + n15] = (_Float16)oacc[dt][r];
  if (n15 == 0) {
    for (int r = 0; r < 4; ++r) {
      Pm[prow + q * 4 + r] = m_r[r];
      Pl[prow + q * 4 + r] = lacc[r];
    }
  }
}

// ---------------- merge the four quarter partials ---------------------
__global__ __launch_bounds__(256) void merge_kernel(
    const _Float16* __restrict__ PO, const float* __restrict__ Pm,
    const float* __restrict__ Pl, float* __restrict__ OUT) {
  int c = blockIdx.x * 256 + threadIdx.x;  // [0, 524288)
  int row = c >> 5, seg = c & 31;
  float m = -1e30f;
  float mh[NQ], lh[NQ];
  for (int h = 0; h < NQ; ++h) {
    mh[h] = Pm[(size_t)h * NROW + row];
    lh[h] = Pl[(size_t)h * NROW + row];
    m = fmaxf(m, mh[h]);
  }
  float l = 0.f;
  float wh[NQ];
  for (int h = 0; h < NQ; ++h) {
    wh[h] = __expf(mh[h] - m);
    l += lh[h] * wh[h];
  }
  float inv = 1.0f / l;
  float o[8];
  for (int j = 0; j < 8; ++j) o[j] = 0.f;
  for (int h = 0; h < NQ; ++h) {
    half8 a = *(const half8*)(PO + ((size_t)h * NROW + row) * D_ + seg * 8);
    float w = wh[h];
    for (int j = 0; j < 8; ++j) o[j] += (float)a[j] * w;
  }
  float* op = OUT + (size_t)row * D_ + seg * 8;
  f32x4 o0 = {o[0] * inv, o[1] * inv, o[2] * inv, o[3] * inv};
  f32x4 o1 = {o[4] * inv, o[5] * inv, o[6] * inv, o[7] * inv};
  *(f32x4*)op = o0;
  *(f32x4*)(op + 4) = o1;
}

extern "C" void kernel_launch(void* const* d_in, const int* in_sizes, int n_in,
                              void* d_out, int out_size, void* d_ws, size_t ws_size,
                              hipStream_t stream) {
  const float* x     = (const float*)d_in[0];  // [8,2048,256]
  const float* y     = (const float*)d_in[1];  // [8,2048,256]
  const int*   ymask = (const int*)  d_in[2];  // [8,2048]
  const float* W     = (const float*)d_in[3];  // [256,256]
  const float* bias  = (const float*)d_in[4];  // [256]
  float* out = (float*)d_out;

  // ws layout (~57 MB)
  char* ws = (char*)d_ws;
  size_t o = 0;
  unsigned short* Whi = (unsigned short*)(ws + o); o += 131072;
  unsigned short* Wlo = (unsigned short*)(ws + o); o += 131072;
  _Float16* XP  = (_Float16*)(ws + o); o += 8388608;
  _Float16* YPc = (_Float16*)(ws + o); o += 8388608;
  _Float16* YTc = (_Float16*)(ws + o); o += 8388608;
  _Float16* PO  = (_Float16*)(ws + o); o += (size_t)NQ * NROW * D_ * 2;  // 32 MB
  float* Pm   = (float*)(ws + o); o += (size_t)NQ * NROW * 4;            // 256 KB
  float* Pl   = (float*)(ws + o); o += (size_t)NQ * NROW * 4;            // 256 KB
  int*   CIDX = (int*)  (ws + o); o += 65536;
  int*   CPOS = (int*)  (ws + o); o += 65536;
  int*   Lc   = (int*)  (ws + o);

  prep_kernel<<<40, 256, 0, stream>>>(W, Whi, Wlo, ymask, CIDX, CPOS, Lc);
  projgather_kernel<<<1536, 256, 0, stream>>>(x, y, bias, Whi, Wlo, CPOS, CIDX, Lc,
                                              XP, YPc, YTc);
  flash_kernel<<<1024, 256, 0, stream>>>(XP, YPc, YTc, Lc, PO, Pm, Pl);
  merge_kernel<<<2048, 256, 0, stream>>>(PO, Pm, Pl, out);
}

// Round 11
// 154.990 us; speedup vs baseline: 1.1103x; 1.0677x over previous
//
#include <hip/hip_runtime.h>

typedef __attribute__((ext_vector_type(8))) short short8;
typedef _Float16 half8 __attribute__((ext_vector_type(8)));
typedef __attribute__((ext_vector_type(4))) float f32x4;
typedef __attribute__((ext_vector_type(4))) unsigned int uint4v;
typedef __attribute__((ext_vector_type(2))) unsigned int uint2v;

#define B_   8
#define LX_  2048
#define LY_  2048
#define D_   256
#define NROW (B_ * LX_)   // 16384

__device__ __forceinline__ unsigned short f2bf(float f) {
  unsigned u = __builtin_bit_cast(unsigned, f);
  u += 0x7FFF + ((u >> 16) & 1);          // RNE truncate (inputs are finite)
  return (unsigned short)(u >> 16);
}
__device__ __forceinline__ float bf2f(unsigned short h) {
  unsigned u = ((unsigned)h) << 16;
  return __builtin_bit_cast(float, u);
}

// ---------------- prep: blocks 0..7 mask scan; blocks 8..39 W split ---
__global__ __launch_bounds__(256) void prep_kernel(
    const float* __restrict__ W, unsigned short* __restrict__ Whi,
    unsigned short* __restrict__ Wlo,
    const int* __restrict__ MASK, int* __restrict__ CIDX, int* __restrict__ Lc) {
  int t = threadIdx.x;
  if (blockIdx.x >= 8) {
    int base = (blockIdx.x - 8) * 2048 + t * 8;
    f32x4 f0 = *(const f32x4*)(W + base);
    f32x4 f1 = *(const f32x4*)(W + base + 4);
    float v[8] = {f0[0], f0[1], f0[2], f0[3], f1[0], f1[1], f1[2], f1[3]};
    unsigned short h[8], l[8];
    for (int j = 0; j < 8; ++j) {
      h[j] = f2bf(v[j]);
      l[j] = f2bf(v[j] - bf2f(h[j]));
    }
    uint4v vh = {(unsigned)h[0] | ((unsigned)h[1] << 16), (unsigned)h[2] | ((unsigned)h[3] << 16),
                 (unsigned)h[4] | ((unsigned)h[5] << 16), (unsigned)h[6] | ((unsigned)h[7] << 16)};
    uint4v vl = {(unsigned)l[0] | ((unsigned)l[1] << 16), (unsigned)l[2] | ((unsigned)l[3] << 16),
                 (unsigned)l[4] | ((unsigned)l[5] << 16), (unsigned)l[6] | ((unsigned)l[7] << 16)};
    *(uint4v*)(Whi + base) = vh;
    *(uint4v*)(Wlo + base) = vl;
    return;
  }
  __shared__ int s[256];
  int b = blockIdx.x;
  int f[8];
  int cnt = 0;
  for (int k = 0; k < 8; ++k) {
    f[k] = (MASK[b * 2048 + t * 8 + k] == 0) ? 1 : 0;
    cnt += f[k];
  }
  s[t] = cnt;
  __syncthreads();
  for (int off = 1; off < 256; off <<= 1) {
    int v = (t >= off) ? s[t - off] : 0;
    __syncthreads();
    s[t] += v;
    __syncthreads();
  }
  if (t == 255) Lc[b] = s[255];
  int off = s[t] - cnt;
  for (int k = 0; k < 8; ++k) {
    int j = t * 8 + k;
    if (f[k]) CIDX[b * 2048 + (off++)] = j;
  }
}

// ---------------- fused: blocks 0..511 proj ; 512..1535 gatherT -------
// proj: relu(in @ W^T + b) exact via bf16 hi/lo split. X-blocks (0..255)
//       process 64 x-rows -> XP. Y-blocks (256..511) process 64 COMPACTED
//       y-slots (gather via CIDX) -> YPc contiguous. LDS-bounce epilogue
//       for coalesced uint4 stores.
// gatherT: compacted y gather + transpose -> YTc fp16 [B][D][j].
__global__ __launch_bounds__(256, 2) void projgather_kernel(
    const float* __restrict__ X, const float* __restrict__ Y,
    const float* __restrict__ bias,
    const unsigned short* __restrict__ Whi, const unsigned short* __restrict__ Wlo,
    const int* __restrict__ CIDX, const int* __restrict__ Lc,
    _Float16* __restrict__ XP, _Float16* __restrict__ YPc,
    _Float16* __restrict__ YTc) {
  __shared__ __align__(16) unsigned char smem[51200];
  int t = threadIdx.x;

  if (blockIdx.x >= 512) {
    // ---------------- gatherT ----------------
    _Float16 (*tile)[72] = (_Float16(*)[72])smem;
    int id = blockIdx.x - 512;
    int db = id & 3, nb = (id >> 2) & 31, b = id >> 7;
    int lc = Lc[b];
    int end = (lc + 31) & ~31;
    if (nb * 64 >= end) return;
    int nl = t >> 2, ds = t & 3;
    int j = nb * 64 + nl;
    int idx = (j < lc) ? CIDX[b * 2048 + j] : 0;
    const float* src = Y + (size_t)(b * LY_ + idx) * D_ + db * 64 + ds * 16;
    for (int i = 0; i < 4; ++i) {
      f32x4 f = *(const f32x4*)(src + i * 4);
      for (int k = 0; k < 4; ++k) tile[ds * 16 + i * 4 + k][nl] = (_Float16)f[k];
    }
    __syncthreads();
    int dl = t >> 2, nsub = t & 3;
    uint4v v0 = *(const uint4v*)&tile[dl][nsub * 16];
    uint4v v1 = *(const uint4v*)&tile[dl][nsub * 16 + 8];
    _Float16* dst = YTc + (size_t)(b * D_ + db * 64 + dl) * LY_ + nb * 64 + nsub * 16;
    *(uint4v*)(dst) = v0;
    *(uint4v*)(dst + 8) = v1;
    return;
  }

  // ---------------- proj ----------------
  unsigned short (*Ah)[40] = (unsigned short(*)[40])(smem);           // 5120
  unsigned short (*Al)[40] = (unsigned short(*)[40])(smem + 5120);    // 5120
  unsigned short (*Bh)[40] = (unsigned short(*)[40])(smem + 10240);   // 20480
  unsigned short (*Bl)[40] = (unsigned short(*)[40])(smem + 30720);   // 20480

  int lane = t & 63, wave = t >> 6;
  int q = lane >> 4, n15 = lane & 15;
  int arow = t >> 2, aseg = t & 3;
  int erow = t >> 2, ec = t & 3;

  bool isX = blockIdx.x < 256;
  int m0 = 0, b = 0, slot0 = 0, lcb = 0;
  const float* arow_ptr;
  if (isX) {
    m0 = blockIdx.x * 64;
    arow_ptr = X + (size_t)(m0 + arow) * D_;
  } else {
    int id = blockIdx.x - 256;
    b = id >> 5;
    int rb = id & 31;
    lcb = Lc[b];
    slot0 = rb * 64;
    if (slot0 >= lcb) return;          // uniform exit, no barriers crossed
    int sl = slot0 + arow;
    int grow = (sl < lcb) ? CIDX[b * 2048 + sl] : 0;
    arow_ptr = Y + (size_t)(b * 2048 + grow) * D_;
  }

  f32x4 acc[4][4];
  for (int mt = 0; mt < 4; ++mt)
    for (int nt = 0; nt < 4; ++nt) acc[mt][nt] = (f32x4){0.f, 0.f, 0.f, 0.f};

  f32x4 pa[2];
  uint4v pbh[4], pbl[4];
#define PROJ_PF(kc)                                                            \
  {                                                                            \
    for (int i = 0; i < 2; ++i)                                                \
      pa[i] = *(const f32x4*)(arow_ptr + (kc) * 32 + (aseg + i * 4) * 4);      \
    for (int p = 0; p < 4; ++p) {                                              \
      int e = p * 64 + erow;                                                   \
      pbh[p] = *(const uint4v*)(Whi + (size_t)e * D_ + (kc) * 32 + ec * 8);    \
      pbl[p] = *(const uint4v*)(Wlo + (size_t)e * D_ + (kc) * 32 + ec * 8);    \
    }                                                                          \
  }

  PROJ_PF(0);

  for (int kc = 0; kc < 8; ++kc) {
    __syncthreads();
    for (int i = 0; i < 2; ++i) {
      int seg = aseg + i * 4;
      f32x4 f = pa[i];
      unsigned short h[4], l[4];
      for (int j = 0; j < 4; ++j) {
        h[j] = f2bf(f[j]);
        l[j] = f2bf(f[j] - bf2f(h[j]));
      }
      uint2v vh = {(unsigned)h[0] | ((unsigned)h[1] << 16),
                   (unsigned)h[2] | ((unsigned)h[3] << 16)};
      uint2v vl = {(unsigned)l[0] | ((unsigned)l[1] << 16),
                   (unsigned)l[2] | ((unsigned)l[3] << 16)};
      *(uint2v*)&Ah[arow][seg * 4] = vh;
      *(uint2v*)&Al[arow][seg * 4] = vl;
    }
    for (int p = 0; p < 4; ++p) {
      int e = p * 64 + erow;
      *(uint4v*)&Bh[e][ec * 8] = pbh[p];
      *(uint4v*)&Bl[e][ec * 8] = pbl[p];
    }
    if (kc < 7) PROJ_PF(kc + 1);
    __syncthreads();

    short8 afh[4], afl[4], bfh[4], bfl[4];
    for (int mt = 0; mt < 4; ++mt) {
      afh[mt] = *(const short8*)&Ah[mt * 16 + n15][q * 8];
      afl[mt] = *(const short8*)&Al[mt * 16 + n15][q * 8];
    }
    for (int nt = 0; nt < 4; ++nt) {
      bfh[nt] = *(const short8*)&Bh[wave * 64 + nt * 16 + n15][q * 8];
      bfl[nt] = *(const short8*)&Bl[wave * 64 + nt * 16 + n15][q * 8];
    }
    for (int mt = 0; mt < 4; ++mt)
      for (int nt = 0; nt < 4; ++nt) {
        acc[mt][nt] = __builtin_amdgcn_mfma_f32_16x16x32_bf16(afh[mt], bfh[nt], acc[mt][nt], 0, 0, 0);
        acc[mt][nt] = __builtin_amdgcn_mfma_f32_16x16x32_bf16(afl[mt], bfh[nt], acc[mt][nt], 0, 0, 0);
        acc[mt][nt] = __builtin_amdgcn_mfma_f32_16x16x32_bf16(afh[mt], bfl[nt], acc[mt][nt], 0, 0, 0);
      }
  }
#undef PROJ_PF

  // ---- epilogue: bias+relu -> LDS bounce -> coalesced uint4 stores
  __syncthreads();                       // all waves done reading Bh/Bl
  _Float16 (*epi)[264] = (_Float16(*)[264])smem;   // 64 x 264 fp16 = 33792 B
  for (int nt = 0; nt < 4; ++nt) {
    int e = wave * 64 + nt * 16 + n15;
    float bv = bias[e];
    for (int mt = 0; mt < 4; ++mt)
      for (int r = 0; r < 4; ++r) {
        float v = acc[mt][nt][r] + bv;
        v = v > 0.f ? v : 0.f;
        epi[mt * 16 + q * 4 + r][e] = (_Float16)v;
      }
  }
  __syncthreads();
  int row = t >> 2, seg = t & 3;
  bool valid = isX || (slot0 + row < lcb);
  if (valid) {
    _Float16* drp = isX ? (XP + (size_t)(m0 + row) * D_)
                        : (YPc + (size_t)(b * 2048 + slot0 + row) * D_);
    for (int k = 0; k < 8; ++k) {
      uint4v v = *(const uint4v*)&epi[row][seg * 64 + k * 8];
      *(uint4v*)(drp + seg * 64 + k * 8) = v;
    }
  }
}

// ---------------- flash attention over COMPACTED y, split halves ------
// grid 512: (b, 64 x-rows, tile-half). 4 waves x 16 rows. tiles of 32 j.
__global__ __launch_bounds__(256, 2) void flash_kernel(
    const _Float16* __restrict__ XP, const _Float16* __restrict__ YPc,
    const _Float16* __restrict__ YTc, const int* __restrict__ Lc,
    _Float16* __restrict__ PO, float* __restrict__ Pm, float* __restrict__ Pl) {
  __shared__ _Float16 yp_t[32][264];   // [j][d], +8 pad
  __shared__ _Float16 yT_t[256][40];   // [d][j], +8 pad
  __shared__ _Float16 pbuf[4][16][40]; // per-wave P round-trip

  int t = threadIdx.x;
  int lane = t & 63, wave = t >> 6;
  int q = lane >> 4, n15 = lane & 15;
  int half = blockIdx.x & 1;
  int xb = (blockIdx.x >> 1) & 31;
  int b = blockIdx.x >> 6;
  int row0 = xb * 64 + wave * 16;

  int lc = Lc[b];
  int T  = (lc + 31) >> 5;
  int T0 = (T + 1) >> 1;
  int tstart = half ? T0 : 0;
  int tend   = half ? T  : T0;

  half8 a[8];
  const _Float16* xrow = XP + (size_t)(b * LX_ + row0 + n15) * D_ + q * 8;
  for (int kk = 0; kk < 8; ++kk) a[kk] = *(const half8*)(xrow + kk * 32);

  half8 lones;
  for (int j = 0; j < 8; ++j) lones[j] = (n15 == 0) ? (_Float16)1 : (_Float16)0;

  float m_r[4];
  for (int r = 0; r < 4; ++r) m_r[r] = -1e30f;
  f32x4 lacc = {0.f, 0.f, 0.f, 0.f};
  f32x4 oacc[16];
  for (int dt = 0; dt < 16; ++dt) oacc[dt] = (f32x4){0.f, 0.f, 0.f, 0.f};

  const _Float16* ypb = YPc + (size_t)b * LY_ * D_;
  const _Float16* yTb = YTc + (size_t)b * D_ * LY_;

  uint4v pr[8];
#define PREFETCH(tt)                                                          \
  {                                                                           \
    int y0p = (tt) * 32;                                                      \
    for (int i = 0; i < 4; ++i) {                                             \
      int c = t + i * 256;                                                    \
      pr[i] = *(const uint4v*)(ypb + (size_t)(y0p + (c >> 5)) * D_ + (c & 31) * 8); \
    }                                                                         \
    for (int i = 0; i < 4; ++i) {                                             \
      int c = t + i * 256;                                                    \
      pr[4 + i] = *(const uint4v*)(yTb + (size_t)(c >> 2) * LY_ + y0p + (c & 3) * 8); \
    }                                                                         \
  }

  if (tstart < tend) PREFETCH(tstart);

  for (int tt = tstart; tt < tend; ++tt) {
    int y0 = tt * 32;
    __syncthreads();
    for (int i = 0; i < 4; ++i) {
      int c = t + i * 256;
      *(uint4v*)&yp_t[c >> 5][(c & 31) * 8] = pr[i];
    }
    for (int i = 0; i < 4; ++i) {
      int c = t + i * 256;
      *(uint4v*)&yT_t[c >> 2][(c & 3) * 8] = pr[4 + i];
    }
    if (tt + 1 < tend) PREFETCH(tt + 1);
    __syncthreads();

    f32x4 S0 = {0.f, 0.f, 0.f, 0.f}, S1 = {0.f, 0.f, 0.f, 0.f};
    for (int kk = 0; kk < 8; ++kk) {
      half8 b0 = *(const half8*)&yp_t[n15][kk * 32 + q * 8];
      S0 = __builtin_amdgcn_mfma_f32_16x16x32_f16(a[kk], b0, S0, 0, 0, 0);
    }
    for (int kk = 0; kk < 8; ++kk) {
      half8 b1 = *(const half8*)&yp_t[16 + n15][kk * 32 + q * 8];
      S1 = __builtin_amdgcn_mfma_f32_16x16x32_f16(a[kk], b1, S1, 0, 0, 0);
    }
    bool mk0 = (y0 + n15) >= lc;
    bool mk1 = (y0 + 16 + n15) >= lc;

    float al[4];
    _Float16 ph0[4], ph1[4];
    bool need = false;
    for (int r = 0; r < 4; ++r) {
      float s0 = mk0 ? -1e30f : S0[r];
      float s1 = mk1 ? -1e30f : S1[r];
      float tm = fmaxf(s0, s1);
      tm = fmaxf(tm, __shfl_xor(tm, 1));
      tm = fmaxf(tm, __shfl_xor(tm, 2));
      tm = fmaxf(tm, __shfl_xor(tm, 4));
      tm = fmaxf(tm, __shfl_xor(tm, 8));
      float mn = fmaxf(m_r[r], tm);
      al[r] = __expf(m_r[r] - mn);
      m_r[r] = mn;
      ph0[r] = (_Float16)__expf(s0 - mn);
      ph1[r] = (_Float16)__expf(s1 - mn);
      need = need || (al[r] != 1.0f);
    }
    if (__ballot(need)) {
      for (int dt = 0; dt < 16; ++dt)
        for (int r = 0; r < 4; ++r) oacc[dt][r] *= al[r];
      for (int r = 0; r < 4; ++r) lacc[r] *= al[r];
    }
    for (int r = 0; r < 4; ++r) {
      pbuf[wave][q * 4 + r][n15] = ph0[r];
      pbuf[wave][q * 4 + r][16 + n15] = ph1[r];
    }
    half8 pa = *(const half8*)&pbuf[wave][n15][q * 8];
    lacc = __builtin_amdgcn_mfma_f32_16x16x32_f16(pa, lones, lacc, 0, 0, 0);
    for (int dt = 0; dt < 16; ++dt) {
      half8 bb = *(const half8*)&yT_t[dt * 16 + n15][q * 8];
      oacc[dt] = __builtin_amdgcn_mfma_f32_16x16x32_f16(pa, bb, oacc[dt], 0, 0, 0);
    }
  }
#undef PREFETCH

  size_t prow = (size_t)(half * B_ + b) * LX_ + row0;
  _Float16* po = PO + prow * D_;
  for (int dt = 0; dt < 16; ++dt)
    for (int r = 0; r < 4; ++r)
      po[(size_t)(q * 4 + r) * D_ + dt * 16 + n15] = (_Float16)oacc[dt][r];
  if (n15 == 0) {
    for (int r = 0; r < 4; ++r) {
      Pm[prow + q * 4 + r] = m_r[r];
      Pl[prow + q * 4 + r] = lacc[r];
    }
  }
}

// ---------------- merge the two tile-half partials --------------------
__global__ __launch_bounds__(256) void merge_kernel(
    const _Float16* __restrict__ PO, const float* __restrict__ Pm,
    const float* __restrict__ Pl, float* __restrict__ OUT) {
  int c = blockIdx.x * 256 + threadIdx.x;
  int row = c >> 5, seg = c & 31;
  float m0 = Pm[row], m1 = Pm[NROW + row];
  float l0 = Pl[row], l1 = Pl[NROW + row];
  float m = fmaxf(m0, m1);
  float w0 = __expf(m0 - m), w1 = __expf(m1 - m);
  float inv = 1.0f / (l0 * w0 + l1 * w1);
  const _Float16* p0 = PO + (size_t)row * D_ + seg * 8;
  const _Float16* p1 = p0 + (size_t)NROW * D_;
  half8 a = *(const half8*)p0;
  half8 bsec = *(const half8*)p1;
  float* o = OUT + (size_t)row * D_ + seg * 8;
  f32x4 o0, o1;
  for (int j = 0; j < 4; ++j) o0[j] = ((float)a[j] * w0 + (float)bsec[j] * w1) * inv;
  for (int j = 0; j < 4; ++j) o1[j] = ((float)a[4 + j] * w0 + (float)bsec[4 + j] * w1) * inv;
  *(f32x4*)o = o0;
  *(f32x4*)(o + 4) = o1;
}

extern "C" void kernel_launch(void* const* d_in, const int* in_sizes, int n_in,
                              void* d_out, int out_size, void* d_ws, size_t ws_size,
                              hipStream_t stream) {
  const float* x     = (const float*)d_in[0];  // [8,2048,256]
  const float* y     = (const float*)d_in[1];  // [8,2048,256]
  const int*   ymask = (const int*)  d_in[2];  // [8,2048]
  const float* W     = (const float*)d_in[3];  // [256,256]
  const float* bias  = (const float*)d_in[4];  // [256]
  float* out = (float*)d_out;

  // ws layout (~41 MB)
  char* ws = (char*)d_ws;
  size_t o = 0;
  unsigned short* Whi = (unsigned short*)(ws + o); o += 131072;
  unsigned short* Wlo = (unsigned short*)(ws + o); o += 131072;
  _Float16* XP  = (_Float16*)(ws + o); o += 8388608;
  _Float16* YPc = (_Float16*)(ws + o); o += 8388608;
  _Float16* YTc = (_Float16*)(ws + o); o += 8388608;
  _Float16* PO  = (_Float16*)(ws + o); o += 16777216;   // 2 halves
  float* Pm   = (float*)(ws + o); o += 131072;
  float* Pl   = (float*)(ws + o); o += 131072;
  int*   CIDX = (int*)  (ws + o); o += 65536;
  int*   Lc   = (int*)  (ws + o);

  prep_kernel<<<40, 256, 0, stream>>>(W, Whi, Wlo, ymask, CIDX, Lc);
  projgather_kernel<<<1536, 256, 0, stream>>>(x, y, bias, Whi, Wlo, CIDX, Lc,
                                              XP, YPc, YTc);
  flash_kernel<<<512, 256, 0, stream>>>(XP, YPc, YTc, Lc, PO, Pm, Pl);
  merge_kernel<<<2048, 256, 0, stream>>>(PO, Pm, Pl, out);
}